// Round 7
// baseline (229.641 us; speedup 1.0000x reference)
//
#include <hip/hip_runtime.h>
#include <stdint.h>

#define BS 8
#define NN 256
#define GD 64
#define ND 64
#define ED 32

// ---------------------------------------------------------------------------
// K1: vj[b,n,o] = V[b,n,:]@Wa_vj[:,o] ; vi[b,n,o] = V[b,n,:]@Wa_vi[:,o]
//     up[b,o]   = u[b,:]@Wa_u[:,o] + b_A[o]
// Scalar-stream: V rows via s_load (wave-uniform addr), W columns in VGPRs.
// Also zeroes colsum/vagg/aagg (ws is re-poisoned 0xAA every call).
// grid = 64 blocks x 256 thr (4 waves x 8 rows = 32 rows/block)
// ---------------------------------------------------------------------------
__global__ __launch_bounds__(256) void k1_proj(
        const float* __restrict__ u, const float* __restrict__ V,
        const float* __restrict__ W_A, const float* __restrict__ b_A,
        float* __restrict__ vj, float* __restrict__ vi, float* __restrict__ up,
        float* __restrict__ colsum, float* __restrict__ vagg) {
    int t = threadIdx.x, blk = blockIdx.x;
    float4 z4 = make_float4(0.f, 0.f, 0.f, 0.f);
    ((float4*)colsum)[blk * 256 + t] = z4;            // 64*256 f4 = 65536 floats
    if (blk == 1 && t < 192) ((float4*)vagg)[t] = z4; // vagg(512)+aagg(256) contiguous

    int wv = __builtin_amdgcn_readfirstlane(t >> 6);  // wave id 0..3
    int o  = t & 31;
    int h  = (t >> 5) & 1;                            // 0 = vj, 1 = vi

    float w2_[ND];                                    // W_A col for (h, o)
#pragma unroll
    for (int k = 0; k < ND; ++k)
        w2_[k] = W_A[(ED + h * ND + k) * ED + o];
    float* dstBase = h ? vi : vj;

    int bn0 = blk * 32 + wv * 8;
#pragma unroll
    for (int r = 0; r < 8; ++r) {
        int bn = bn0 + r;
        const float* vr = V + (size_t)bn * ND;        // wave-uniform -> s_load
        float a0 = 0.f, a1 = 0.f;
#pragma unroll
        for (int k = 0; k < ND; k += 2) {
            a0 = fmaf(vr[k + 0], w2_[k + 0], a0);
            a1 = fmaf(vr[k + 1], w2_[k + 1], a1);
        }
        dstBase[bn * ED + o] = a0 + a1;
    }

    if (blk < 8 && t < 32) {
        float a2 = b_A[t];
#pragma unroll 8
        for (int k = 0; k < GD; ++k)
            a2 = fmaf(u[blk * GD + k], W_A[(ED + 2 * ND + k) * ED + t], a2);
        up[blk * ED + t] = a2;
    }
}

// ---------------------------------------------------------------------------
// K2: A_prime[b,i,j,o] = relu(A[b,i,j,:]@Wa_e[:,o] + vj[b,j,o] + vi[b,i,o] + up[b,o])
//     colsum[b,j,o] += sum_i
// Scalar-stream: each wave owns ONE j, loops 64 i in pairs. A rows are
// wave-uniform -> s_load_dwordx16; lane o holds W column in 32 VGPRs; every
// lane computes both rows of the pair, selects its half (h) for the store.
// grid = 8b x 4ic x 64jc = 2048 blocks x 256 thr. No LDS, no barriers.
// ---------------------------------------------------------------------------
__global__ __launch_bounds__(256) void k2_main(
        const float* __restrict__ A, const float* __restrict__ W_A,
        const float* __restrict__ vj, const float* __restrict__ vi,
        const float* __restrict__ up,
        float* __restrict__ Aprime, float* __restrict__ colsum) {
    int bid = blockIdx.x;
    int b   = bid >> 8;            // 8
    int ic  = (bid >> 6) & 3;      // 4  -> i0 = ic*64
    int jc  = bid & 63;            // 64 -> j0 = jc*4
    int t   = threadIdx.x;
    int wv  = __builtin_amdgcn_readfirstlane(t >> 6);
    int j   = jc * 4 + wv;
    int o   = t & 31;
    int h   = (t >> 5) & 1;
    int i0  = ic * 64;

    float w_[ED];
#pragma unroll
    for (int e = 0; e < ED; ++e) w_[e] = W_A[e * ED + o];
    float cj = vj[(b * NN + j) * ED + o] + up[b * ED + o];

    const float* Ab = A      + ((size_t)(b * NN + i0) * NN + j) * ED;
    float*       Pb = Aprime + ((size_t)(b * NN + i0) * NN + j) * ED;
    const float* vib = vi + (size_t)(b * NN + i0) * ED + o;

    float colacc = 0.f;
    for (int i = 0; i < 64; i += 2) {
        const float* r0 = Ab + (size_t)i * (NN * ED);  // wave-uniform -> s_load
        const float* r1 = r0 + NN * ED;
        float a0 = 0.f, a1 = 0.f, c0 = 0.f, c1 = 0.f;
#pragma unroll
        for (int e = 0; e < ED; e += 2) {
            a0 = fmaf(r0[e + 0], w_[e + 0], a0);
            a1 = fmaf(r0[e + 1], w_[e + 1], a1);
            c0 = fmaf(r1[e + 0], w_[e + 0], c0);
            c1 = fmaf(r1[e + 1], w_[e + 1], c1);
        }
        float vA = fmaxf(a0 + a1 + cj + vib[(size_t)(i + 0) * ED], 0.f);
        float vB = fmaxf(c0 + c1 + cj + vib[(size_t)(i + 1) * ED], 0.f);
        float v  = h ? vB : vA;
        Pb[(size_t)(i + h) * (NN * ED) + o] = v;       // 64 lanes, 2x128B rows
        colacc += v;
    }
    colacc += __shfl_xor(colacc, 32, 64);              // fold h-halves
    if (h == 0) atomicAdd(&colsum[(b * NN + j) * ED + o], colacc);
}

// ---------------------------------------------------------------------------
// K3: V_prime[b,n,d] = relu([colsum/256, V, u] @ W_v + b_v)
// Each wave owns a 40-row k-slice of W_v (VGPRs); xv pieces read scalar from
// global (colsum / V / u, all wave-uniform rows); cross-wave reduce in LDS.
// Also emits vagg (sum of Vprime rows) and aagg (sum of colsum rows) partials.
// grid = 256 blocks x 256 thr; 8 rows per block.
// ---------------------------------------------------------------------------
__global__ __launch_bounds__(256) void k3_vprime(
        const float* __restrict__ V, const float* __restrict__ u,
        const float* __restrict__ W_v, const float* __restrict__ b_v,
        const float* __restrict__ colsum, float* __restrict__ Vprime,
        float* __restrict__ vagg, float* __restrict__ aagg) {
    __shared__ float red[4][8][ND];   // 8 KB
    int t   = threadIdx.x;
    int blk = blockIdx.x;
    int bn0 = blk * 8;
    int b   = blk >> 5;
    int wv  = __builtin_amdgcn_readfirstlane(t >> 6);
    int d   = t & 63;

    float w_[40];
#pragma unroll
    for (int kk = 0; kk < 40; ++kk)
        w_[kk] = W_v[(wv * 40 + kk) * ND + d];
    if (wv == 0) {                      // fold the 1/256 into the weights
#pragma unroll
        for (int kk = 0; kk < 32; ++kk) w_[kk] *= (1.f / 256.f);
    }

    const float* ur = u + (size_t)b * GD;
    float acc[8];
#pragma unroll
    for (int r = 0; r < 8; ++r) {
        int bn = bn0 + r;
        const float* cs = colsum + (size_t)bn * ED;
        const float* Vr = V + (size_t)bn * ND;
        float a0 = 0.f, a1 = 0.f;
        if (wv == 0) {                  // k 0..39: colsum[0..31], V[0..7]
#pragma unroll
            for (int kk = 0; kk < 32; kk += 2) {
                a0 = fmaf(cs[kk + 0], w_[kk + 0], a0);
                a1 = fmaf(cs[kk + 1], w_[kk + 1], a1);
            }
#pragma unroll
            for (int kk = 32; kk < 40; kk += 2) {
                a0 = fmaf(Vr[kk - 32], w_[kk + 0], a0);
                a1 = fmaf(Vr[kk - 31], w_[kk + 1], a1);
            }
        } else if (wv == 1) {           // k 40..79: V[8..47]
#pragma unroll
            for (int kk = 0; kk < 40; kk += 2) {
                a0 = fmaf(Vr[kk + 8], w_[kk + 0], a0);
                a1 = fmaf(Vr[kk + 9], w_[kk + 1], a1);
            }
        } else if (wv == 2) {           // k 80..119: V[48..63], u[0..23]
#pragma unroll
            for (int kk = 0; kk < 16; kk += 2) {
                a0 = fmaf(Vr[48 + kk], w_[kk + 0], a0);
                a1 = fmaf(Vr[49 + kk], w_[kk + 1], a1);
            }
#pragma unroll
            for (int kk = 16; kk < 40; kk += 2) {
                a0 = fmaf(ur[kk - 16], w_[kk + 0], a0);
                a1 = fmaf(ur[kk - 15], w_[kk + 1], a1);
            }
        } else {                        // k 120..159: u[24..63]
#pragma unroll
            for (int kk = 0; kk < 40; kk += 2) {
                a0 = fmaf(ur[24 + kk], w_[kk + 0], a0);
                a1 = fmaf(ur[25 + kk], w_[kk + 1], a1);
            }
        }
        acc[r] = a0 + a1;
    }
#pragma unroll
    for (int r = 0; r < 8; ++r) red[wv][r][d] = acc[r];
    __syncthreads();

    int r  = t >> 5;          // 0..7
    int dd = t & 31;
#pragma unroll
    for (int half = 0; half < 2; ++half) {
        int d2 = dd + half * 32;
        float s = red[0][r][d2] + red[1][r][d2] + red[2][r][d2] + red[3][r][d2]
                + b_v[d2];
        s = fmaxf(s, 0.f);
        Vprime[(size_t)(bn0 + r) * ND + d2] = s;
        atomicAdd(&vagg[b * ND + d2], s);
    }
    atomicAdd(&aagg[b * ED + dd], colsum[(size_t)(bn0 + r) * ED + dd]);
}

// ---------------------------------------------------------------------------
// K4: u_prime = relu([aagg/65536, vagg/256, u] @ W_u + b_u). grid = 8 x 64 thr
// ---------------------------------------------------------------------------
__global__ __launch_bounds__(64) void k4_uprime(
        const float* __restrict__ u,
        const float* __restrict__ W_u, const float* __restrict__ b_u,
        const float* __restrict__ vagg, const float* __restrict__ aagg,
        float* __restrict__ uprime) {
    int b = blockIdx.x;
    int t = threadIdx.x;       // 0..63
    __shared__ float xu[ED + ND + GD];
    if (t < 32) xu[t] = aagg[b * ED + t] * (1.f / 65536.f);
    xu[ED + t]      = vagg[b * ND + t] * (1.f / 256.f);
    xu[ED + ND + t] = u[b * GD + t];
    __syncthreads();
    float acc = b_u[t];
#pragma unroll 8
    for (int k = 0; k < ED + ND + GD; ++k)
        acc = fmaf(xu[k], W_u[k * GD + t], acc);
    uprime[b * GD + t] = fmaxf(acc, 0.f);
}

// ---------------------------------------------------------------------------
extern "C" void kernel_launch(void* const* d_in, const int* in_sizes, int n_in,
                              void* d_out, int out_size, void* d_ws, size_t ws_size,
                              hipStream_t stream) {
    const float* u   = (const float*)d_in[0];
    const float* V   = (const float*)d_in[1];
    const float* A   = (const float*)d_in[2];
    const float* W_A = (const float*)d_in[3];
    const float* b_A = (const float*)d_in[4];
    const float* W_v = (const float*)d_in[5];
    const float* b_v = (const float*)d_in[6];
    const float* W_u = (const float*)d_in[7];
    const float* b_u = (const float*)d_in[8];

    float* out    = (float*)d_out;
    float* uprime = out;                           // 8*64
    float* Vprime = out + BS * GD;                 // 8*256*64
    float* Aprime = out + BS * GD + BS * NN * ND;  // 8*256*256*32

    float* ws     = (float*)d_ws;
    float* vj     = ws;                            // BS*NN*ED (65536 f)
    float* vi     = vj + BS * NN * ED;             // BS*NN*ED
    float* up     = vi + BS * NN * ED;             // BS*ED (256 f)
    float* colsum = up + BS * ED;                  // BS*NN*ED (65536 f)
    float* vagg   = colsum + BS * NN * ED;         // BS*ND (512 f)
    float* aagg   = vagg + BS * ND;                // BS*ED (256 f) — contiguous after vagg

    hipLaunchKernelGGL(k1_proj, dim3(64), dim3(256), 0, stream,
                       u, V, W_A, b_A, vj, vi, up, colsum, vagg);
    hipLaunchKernelGGL(k2_main, dim3(2048), dim3(256), 0, stream,
                       A, W_A, vj, vi, up, Aprime, colsum);
    hipLaunchKernelGGL(k3_vprime, dim3(256), dim3(256), 0, stream,
                       V, u, W_v, b_v, colsum, Vprime, vagg, aagg);
    hipLaunchKernelGGL(k4_uprime, dim3(BS), dim3(64), 0, stream,
                       u, W_u, b_u, vagg, aagg, uprime);
}

// Round 9
// 162.752 us; speedup vs baseline: 1.4110x; 1.4110x over previous
//
#include <hip/hip_runtime.h>
#include <stdint.h>

#define BS 8
#define NN 256
#define GD 64
#define ND 64
#define ED 32

#define GLOBAL_AS __attribute__((address_space(1)))
#define LDS_AS    __attribute__((address_space(3)))

// ---------------------------------------------------------------------------
// K1: vj[b,n,o] = V[b,n,:]@Wa_vj[:,o] ; vi[b,n,o] = V[b,n,:]@Wa_vi[:,o]
//     up[b,o]   = u[b,:]@Wa_u[:,o] + b_A[o]
// Also zeroes colsum/vagg/aagg (ws re-poisoned 0xAA before every call).
// grid = 64 blocks x 256 thr; 32 V-rows per block; W_vj|W_vi staged in LDS
// ---------------------------------------------------------------------------
__global__ __launch_bounds__(256) void k1_proj(
        const float* __restrict__ u, const float* __restrict__ V,
        const float* __restrict__ W_A, const float* __restrict__ b_A,
        float* __restrict__ vj, float* __restrict__ vi, float* __restrict__ up,
        float* __restrict__ colsum) {
    __shared__ float W2[2 * ND][ED];   // 16KB: W_A rows ED..ED+127
    __shared__ float Vt[32][ND];       // 8KB
    int t   = threadIdx.x;
    int blk = blockIdx.x;
    int bn0 = blk * 32;
    // zero colsum (65536f) + vagg (512f) + aagg (256f) = 66304 floats
    {
        float4 z4 = make_float4(0.f, 0.f, 0.f, 0.f);
        ((float4*)colsum)[blk * 256 + t] = z4;
        if (blk == 0 && t < 192) ((float4*)(colsum + BS * NN * ED))[t] = z4;
    }
    {
        const float4* src = (const float4*)(W_A + ED * ED);
        float4* dst = (float4*)&W2[0][0];
#pragma unroll
        for (int r = 0; r < 4; ++r) dst[r * 256 + t] = src[r * 256 + t];
    }
    {
        const float4* src = (const float4*)(V + (size_t)bn0 * ND);
        float4* dst = (float4*)&Vt[0][0];
        dst[t]       = src[t];
        dst[256 + t] = src[256 + t];
    }
    __syncthreads();
    int rq  = t >> 6;          // 0..3
    int oo  = t & 63;
    int mat = oo >> 5;         // 0 = vj, 1 = vi
    int o   = oo & 31;
#pragma unroll 2
    for (int p = 0; p < 8; ++p) {
        int rl = p * 4 + rq;
        int bn = bn0 + rl;
        float d0 = 0.f, d1 = 0.f, d2 = 0.f, d3 = 0.f;
#pragma unroll
        for (int k = 0; k < ND; k += 4) {
            d0 = fmaf(Vt[rl][k + 0], W2[mat * ND + k + 0][o], d0);
            d1 = fmaf(Vt[rl][k + 1], W2[mat * ND + k + 1][o], d1);
            d2 = fmaf(Vt[rl][k + 2], W2[mat * ND + k + 2][o], d2);
            d3 = fmaf(Vt[rl][k + 3], W2[mat * ND + k + 3][o], d3);
        }
        float acc = (d0 + d1) + (d2 + d3);
        if (mat == 0) vj[bn * ED + o] = acc;
        else          vi[bn * ED + o] = acc;
    }
    if (blk < 8 && t < 32) {
        float a2 = b_A[t];
#pragma unroll 8
        for (int k = 0; k < GD; ++k)
            a2 = fmaf(u[blk * GD + k], W_A[(ED + 2 * ND + k) * ED + t], a2);
        up[blk * ED + t] = a2;
    }
}

// ---------------------------------------------------------------------------
// K2: A_prime[b,i,j,o] = relu(A[b,i,j,:]@Wa_e[:,o] + vj[b,j,o] + vi[b,i,o] + up[b,o])
//     colsum[b,j,o] += sum over the block's 16 i's (atomic, 16 adds/addr)
// grid = BS*16*32 = 4096 blocks x 256 thr. Tile: 16 i x 8 j.
// A staged via global_load_lds width-16; A_prime stored nontemporal (never
// re-read -> keep L3 for A).
// ---------------------------------------------------------------------------
__global__ __launch_bounds__(256) void k2_main(
        const float* __restrict__ A, const float* __restrict__ W_A,
        const float* __restrict__ vj, const float* __restrict__ vi,
        const float* __restrict__ up,
        float* __restrict__ Aprime, float* __restrict__ colsum) {
    __shared__ float tile[16][8][ED];   // 16KB [i][j][e]
    __shared__ float vit[16][ED];       // 2KB
    int bid = blockIdx.x;
    int b   = bid >> 9;            // /512
    int it  = (bid >> 5) & 15;
    int jc  = bid & 31;
    int t    = threadIdx.x;
    int lane = t & 63;
    int wv   = t >> 6;             // wave id 0..3
    int i0 = it * 16;
    int j0 = jc * 8;

    const float* Asrc = A + ((size_t)(b * NN + i0) * NN + j0) * ED;
#pragma unroll
    for (int r = 0; r < 4; ++r) {
        int il = r * 4 + wv;                       // wave-uniform
        const float* g = Asrc + (size_t)il * NN * ED + lane * 4;
        __builtin_amdgcn_global_load_lds((const GLOBAL_AS void*)g,
                                         (LDS_AS void*)&tile[il][0][0], 16, 0, 0);
    }
    {
        const float* vsrc = vi + (size_t)(b * NN + i0) * ED;
        ((float*)vit)[t]       = vsrc[t];
        ((float*)vit)[t + 256] = vsrc[t + 256];
    }
    int jloc = t >> 5;
    int o    = t & 31;
    int j    = j0 + jloc;
    float w_[ED];
#pragma unroll
    for (int e = 0; e < ED; ++e) w_[e] = W_A[e * ED + o];
    float cj = vj[(b * NN + j) * ED + o] + up[b * ED + o];

    __syncthreads();

    float colacc = 0.f;
    float* Pb = Aprime + ((size_t)(b * NN + i0) * NN + j) * ED + o;
#pragma unroll 2
    for (int ii = 0; ii < 16; ++ii) {
        const float4* lr = (const float4*)(&tile[ii][jloc][0]);
        float d0 = 0.f, d1 = 0.f, d2 = 0.f, d3 = 0.f;
#pragma unroll
        for (int q = 0; q < 8; ++q) {
            float4 f = lr[q];
            d0 = fmaf(f.x, w_[4 * q + 0], d0);
            d1 = fmaf(f.y, w_[4 * q + 1], d1);
            d2 = fmaf(f.z, w_[4 * q + 2], d2);
            d3 = fmaf(f.w, w_[4 * q + 3], d3);
        }
        float v = (d0 + d1) + (d2 + d3) + cj + vit[ii][o];
        v = fmaxf(v, 0.f);
        __builtin_nontemporal_store(v, &Pb[(size_t)ii * NN * ED]);
        colacc += v;
    }
    atomicAdd(&colsum[(b * NN + j) * ED + o], colacc);
}

// ---------------------------------------------------------------------------
// K3: V_prime[b,n,d] = relu([colsum/256, V, u] @ W_v + b_v)
// Also emits block-reduced vagg (sum Vprime rows) and aagg (sum colsum rows).
// grid = 128 blocks x 256 thr; 16 rows per block; W_v staged in LDS (40KB)
// ---------------------------------------------------------------------------
__global__ __launch_bounds__(256) void k3_vprime(
        const float* __restrict__ V, const float* __restrict__ u,
        const float* __restrict__ W_v, const float* __restrict__ b_v,
        const float* __restrict__ colsum, float* __restrict__ Vprime,
        float* __restrict__ vagg, float* __restrict__ aagg) {
    __shared__ float Wv[ED + ND + GD][ND];   // 160x64 = 40KB
    __shared__ float xv[16][ED + ND + GD + 1];
    __shared__ float vred[4][ND];
    __shared__ float ared[4][ED];
    int t = threadIdx.x;
    {
        const float4* src = (const float4*)W_v;
        float4* dst = (float4*)&Wv[0][0];
#pragma unroll
        for (int r = 0; r < 10; ++r) dst[r * 256 + t] = src[r * 256 + t];
    }
    int bn0 = blockIdx.x * 16;
    int b   = bn0 >> 8;
    int d  = t & 63;
    int rq = t >> 6;
#pragma unroll
    for (int p = 0; p < 4; ++p) {
        int rl = p * 4 + rq;
        int bn = bn0 + rl;
        if (d < 32) xv[rl][d] = colsum[bn * ED + d] * (1.f / 256.f);
        xv[rl][ED + d]      = V[(size_t)bn * ND + d];
        xv[rl][ED + ND + d] = u[b * GD + d];
    }
    __syncthreads();
    float vsum = 0.f;
#pragma unroll 2
    for (int p = 0; p < 4; ++p) {
        int rl = p * 4 + rq;
        float acc = b_v[d];
#pragma unroll 8
        for (int k = 0; k < ED + ND + GD; ++k)
            acc = fmaf(xv[rl][k], Wv[k][d], acc);
        acc = fmaxf(acc, 0.f);
        Vprime[(size_t)(bn0 + rl) * ND + d] = acc;
        vsum += acc;
    }
    vred[rq][d] = vsum;
    if (d < 32) {
        float asum = xv[rq][d] + xv[4 + rq][d] + xv[8 + rq][d] + xv[12 + rq][d];
        ared[rq][d] = asum;            // note: carries the 1/256 factor
    }
    __syncthreads();
    if (t < 64) {
        atomicAdd(&vagg[b * ND + t],
                  vred[0][t] + vred[1][t] + vred[2][t] + vred[3][t]);
    } else if (t < 96) {
        int o = t - 64;
        atomicAdd(&aagg[b * ED + o],
                  ared[0][o] + ared[1][o] + ared[2][o] + ared[3][o]);
    }
}

// ---------------------------------------------------------------------------
// K4: u_prime = relu([aagg/256, vagg/256, u] @ W_u + b_u). grid = 8 x 64 thr
// (aagg already carries 1/256 from k3; /256 more gives /65536 total.)
// ---------------------------------------------------------------------------
__global__ __launch_bounds__(64) void k4_uprime(
        const float* __restrict__ u,
        const float* __restrict__ W_u, const float* __restrict__ b_u,
        const float* __restrict__ vagg, const float* __restrict__ aagg,
        float* __restrict__ uprime) {
    int b = blockIdx.x;
    int t = threadIdx.x;       // 0..63
    __shared__ float xu[ED + ND + GD];
    if (t < 32) xu[t] = aagg[b * ED + t] * (1.f / 256.f);
    xu[ED + t]      = vagg[b * ND + t] * (1.f / 256.f);
    xu[ED + ND + t] = u[b * GD + t];
    __syncthreads();
    float acc = b_u[t];
#pragma unroll 8
    for (int k = 0; k < ED + ND + GD; ++k)
        acc = fmaf(xu[k], W_u[k * GD + t], acc);
    uprime[b * GD + t] = fmaxf(acc, 0.f);
}

// ---------------------------------------------------------------------------
extern "C" void kernel_launch(void* const* d_in, const int* in_sizes, int n_in,
                              void* d_out, int out_size, void* d_ws, size_t ws_size,
                              hipStream_t stream) {
    const float* u   = (const float*)d_in[0];
    const float* V   = (const float*)d_in[1];
    const float* A   = (const float*)d_in[2];
    const float* W_A = (const float*)d_in[3];
    const float* b_A = (const float*)d_in[4];
    const float* W_v = (const float*)d_in[5];
    const float* b_v = (const float*)d_in[6];
    const float* W_u = (const float*)d_in[7];
    const float* b_u = (const float*)d_in[8];

    float* out    = (float*)d_out;
    float* uprime = out;                           // 8*64
    float* Vprime = out + BS * GD;                 // 8*256*64
    float* Aprime = out + BS * GD + BS * NN * ND;  // 8*256*256*32

    float* ws     = (float*)d_ws;
    float* vj     = ws;                            // BS*NN*ED (65536 f)
    float* vi     = vj + BS * NN * ED;             // BS*NN*ED
    float* up     = vi + BS * NN * ED;             // BS*ED (256 f)
    float* colsum = up + BS * ED;                  // BS*NN*ED (65536 f)
    float* vagg   = colsum + BS * NN * ED;         // BS*ND (512 f)
    float* aagg   = vagg + BS * ND;                // BS*ED (256 f)

    hipLaunchKernelGGL(k1_proj, dim3(64), dim3(256), 0, stream,
                       u, V, W_A, b_A, vj, vi, up, colsum);
    hipLaunchKernelGGL(k2_main, dim3(4096), dim3(256), 0, stream,
                       A, W_A, vj, vi, up, Aprime, colsum);
    hipLaunchKernelGGL(k3_vprime, dim3(128), dim3(256), 0, stream,
                       V, u, W_v, b_v, colsum, Vprime, vagg, aagg);
    hipLaunchKernelGGL(k4_uprime, dim3(BS), dim3(64), 0, stream,
                       u, W_u, b_u, vagg, aagg, uprime);
}